// Round 8
// baseline (125.956 us; speedup 1.0000x reference)
//
#include <hip/hip_runtime.h>
#include <hip/hip_bf16.h>
#include <hip/hip_fp16.h>
#include <stdint.h>

#define K_DIM 4096
#define N_DIM 11008
#define M_DIM 512
#define PK_ROW 5504          // int32 code-words per k-row (one per n-pair)
#define SC_ROW 172           // scale blocks per k-row

typedef __attribute__((ext_vector_type(4))) float f32x4;
typedef __attribute__((ext_vector_type(4))) int i32x4;
typedef __attribute__((ext_vector_type(4))) unsigned int u32x4;
typedef __attribute__((ext_vector_type(8))) _Float16 half8;
typedef __attribute__((ext_vector_type(8))) short bf16x8;

__constant__ float NF4[16] = {
    -1.0f, -0.6961928009986877f, -0.5250730514526367f, -0.39491748809814453f,
    -0.28444138169288635f, -0.18477343022823334f, -0.09105003625154495f, 0.0f,
    0.07958029955625534f, 0.16093020141124725f, 0.24611230194568634f,
    0.33791524171829224f, 0.44070982933044434f, 0.5626170039176941f,
    0.7229568362236023f, 1.0f};

union H8 { u32x4 v; half8 h; };

__device__ __forceinline__ unsigned h2mul(unsigned a, unsigned b) {
  union { __half2 h; unsigned u; } x, y, r;
  x.u = a; y.u = b;
  r.h = x.h * y.h;           // v_pk_mul_f16
  return r.u;
}
__device__ __forceinline__ unsigned hpack(float a, float b) {
  union { __half2 h; unsigned u; } c;
  c.h = __floats2half2_rn(a, b);
  return c.u;
}
__device__ __forceinline__ unsigned f2bf(float v) {  // for fallback kernel
  union { __hip_bfloat16 h; unsigned short u; } cv;
  cv.h = __float2bfloat16(v);
  return (unsigned)cv.u;
}
// global -> LDS direct DMA, 16B/lane. LDS dest = uniform base + lane*16 (HW).
__device__ __forceinline__ void gld16(const unsigned* g, unsigned* l) {
  __builtin_amdgcn_global_load_lds(
      (const __attribute__((address_space(1))) unsigned*)(const void*)g,
      (__attribute__((address_space(3))) unsigned*)(void*)l, 16, 0, 0);
}

// ---- pre-pass 1: x fp32 -> f16, MFMA-fragment-block layout ----
// unit (m16,k32) = 1KB; u32 idx = (m16*128+k32)*256 + lane*4
// lane l: A[m16*16+(l&15)][k32*32+(l>>4)*8 .. +8)
__global__ __launch_bounds__(256) void conv_a16(const float* __restrict__ x,
                                                unsigned* __restrict__ wsa) {
  const int wid = blockIdx.x * 4 + (threadIdx.x >> 6);
  const int lane = threadIdx.x & 63;
  const int m16 = wid >> 7, k32 = wid & 127;
  const int m = m16 * 16 + (lane & 15);
  const int k = k32 * 32 + (lane >> 4) * 8;
  const float* src = x + (size_t)m * K_DIM + k;
  f32x4 v0 = *(const f32x4*)src;
  f32x4 v1 = *(const f32x4*)(src + 4);
  u32x4 d;
  d[0] = hpack(v0[0], v0[1]);
  d[1] = hpack(v0[2], v0[3]);
  d[2] = hpack(v1[0], v1[1]);
  d[3] = hpack(v1[2], v1[3]);
  *(u32x4*)(wsa + (size_t)wid * 256 + lane * 4) = d;
}

// ---- pre-pass 2: transpose-compact codes ----
// out: uint8 byte (n, kp) = code(2kp,n)<<4 | code(2kp+1,n), stored as dwords:
//      dword D = ((n>>4)*512 + (kp>>2))*16 + (n&15)
__global__ __launch_bounds__(256) void prep_codes(const int* __restrict__ packed,
                                                  unsigned* __restrict__ codes) {
  const int b = blockIdx.x;
  const int kt = b & 63;   // k-tile of 64
  const int nt = b >> 6;   // n-tile of 128 (0..85)
  __shared__ unsigned char Sb[128 * 36];  // [n_local][kp_local], pad 36
  const int t = threadIdx.x;
  const int npl = t & 63;
  const int kq = t >> 6;
  const int np = nt * 64 + npl;
#pragma unroll
  for (int i = 0; i < 8; ++i) {
    const int kpl = kq + i * 4;               // 0..31
    const int k = kt * 64 + kpl * 2;
    const int w0 = packed[(size_t)k * PK_ROW + np];
    const int w1 = packed[(size_t)(k + 1) * PK_ROW + np];
    Sb[(npl * 2) * 36 + kpl] =
        (unsigned char)((((w0 >> 4) & 15) << 4) | ((w1 >> 4) & 15));  // even n
    Sb[(npl * 2 + 1) * 36 + kpl] =
        (unsigned char)(((w0 & 15) << 4) | (w1 & 15));                // odd n
  }
  __syncthreads();
#pragma unroll
  for (int i = 0; i < 4; ++i) {
    const int lin = t + 256 * i;              // 0..1023
    const int n16 = lin & 15;
    const int kp4l = (lin >> 4) & 7;
    const int nb16l = lin >> 7;               // 0..7
    const unsigned v = *(const unsigned*)(Sb + (nb16l * 16 + n16) * 36 + kp4l * 4);
    const size_t D = ((size_t)(nt * 8 + nb16l) * 512 + kt * 8 + kp4l) * 16 + n16;
    codes[D] = v;
  }
}

// ---- pre-pass 3: scales fp32 [k][nb] -> f16x2 pairs [nb][kp] ----
__global__ __launch_bounds__(256) void prep_scales(const float* __restrict__ scales,
                                                   unsigned* __restrict__ scalesp) {
  const int g = blockIdx.x * 256 + threadIdx.x;
  if (g >= SC_ROW * 2048) return;
  const int kp = g / SC_ROW;
  const int nb = g - kp * SC_ROW;
  const float s0 = scales[(size_t)(2 * kp) * SC_ROW + nb];
  const float s1 = scales[(size_t)(2 * kp + 1) * SC_ROW + nb];
  scalesp[(size_t)nb * 2048 + kp] = hpack(s0, s1);
}

// ---- main: fused NF4 GEMM, f16 MFMA ----
// R8: block 128m x 128n, 4 waves 2x2, wave-tile 64m x 64n (nm=nn=4).
// LDS bytes/MFMA = 1KB/nn + 1KB/nm = 512B -> LDS pipe ~= MFMA pipe (R7 was
// nm=2: 768B/MFMA + 2:1 gather ratio -> LDS+VALU serialized at 98us).
// A staged per block via global_load_lds (2x16KB dbuf, 1 barrier/chunk);
// B dequant-on-read via 32-copy LUT (gather bytes == staged-read bytes, so
// staging B would only add traffic). Grid 344 = 8x43.
__global__ __launch_bounds__(256, 3) void nf4_gemm16(
    const unsigned* __restrict__ codes, const unsigned* __restrict__ scalesp,
    const unsigned* __restrict__ wsa, const float* __restrict__ bias,
    float* __restrict__ out) {
  __shared__ unsigned LutR[256 * 32];               // replicated LUT, 32KB
  __shared__ __align__(16) unsigned Alds[2][4096];  // A dbuf 2x16KB

  const int bid = blockIdx.x;
  const int swz = (bid & 7) * 43 + (bid >> 3);      // 344 = 8*43 bijective
  const int m_tile = (swz / 86) * 128;              // 4 m-tiles
  const int n_tile = (swz % 86) * 128;              // 86 n-tiles

  const int t = threadIdx.x;
  {  // replicated LUT: dword idx = byte*32 + copy; lane uses copy=lane&31
    const int c = t & 31;
    const int b0 = t >> 5;
#pragma unroll
    for (int i = 0; i < 32; ++i) {
      const int b = b0 + 8 * i;
      LutR[b * 32 + c] = hpack(NF4[(b >> 4) & 15], NF4[b & 15]);
    }
  }

  const int lane = t & 63;
  const int wid = t >> 6;
  const int wm2 = wid >> 1;            // wave m-half (64 rows)
  const int wnh = wid & 1;             // wave n-half (64 cols)
  const int l15 = lane & 15;
  const int kslice = lane >> 4;
  const int lb = lane & 31;
  const int nf0 = (n_tile >> 4) + wnh * 4;   // first of wave's 4 n16 blocks
  const int nb64 = (n_tile >> 6) + wnh;

  unsigned cb[4];
#pragma unroll
  for (int j = 0; j < 4; ++j) cb[j] = (unsigned)(nf0 + j) * 8192 + lane;
  const unsigned sb = (unsigned)nb64 * 2048 + kslice * 4;

  f32x4 acc[4][4];
#pragma unroll
  for (int i = 0; i < 4; ++i)
#pragma unroll
    for (int j = 0; j < 4; ++j) acc[i][j] = (f32x4){0.f, 0.f, 0.f, 0.f};

  // stage chunk ch (128m x 64k = 16 units of 1KB); wave wid stages units
  // wid*4..wid*4+3; unit u' -> (m16l = u'>>1, k32l = u'&1)
  auto stageA = [&](int ch, int bufi) {
    const int u0 = wid * 4;
#pragma unroll
    for (int u = 0; u < 4; ++u) {
      const int ul = u0 + u;
      const unsigned ug = (unsigned)((m_tile >> 4) + (ul >> 1)) * 128 + ch * 2 + (ul & 1);
      gld16(wsa + (size_t)ug * 256 + lane * 4, &Alds[bufi][ul * 256]);
    }
  };
  // codes+scales for chunk ch -> regs (8 dwords + 2 x4)
  auto loadB = [&](int ch, unsigned* c, u32x4* sv) {
#pragma unroll
    for (int ks = 0; ks < 2; ++ks) {
      const unsigned so = 64u * (unsigned)(2 * ch + ks);
#pragma unroll
      for (int j = 0; j < 4; ++j) c[ks * 4 + j] = codes[cb[j] + so];
      sv[ks] = *(const u32x4*)(scalesp + sb + 16u * (unsigned)(2 * ch + ks));
    }
  };
  auto compute = [&](int cur, const unsigned* c, const u32x4* sv) {
#pragma unroll
    for (int ks = 0; ks < 2; ++ks) {
      H8 a[4];
#pragma unroll
      for (int fm = 0; fm < 4; ++fm)
        a[fm].v = *(const u32x4*)(&Alds[cur][((wm2 * 4 + fm) * 2 + ks) * 256 + lane * 4]);
      const u32x4 s4 = sv[ks];
#pragma unroll
      for (int j = 0; j < 4; ++j) {
        const unsigned cw = c[ks * 4 + j];
        H8 B;
        B.v[0] = h2mul(LutR[((cw & 255u) << 5) | lb], s4[0]);
        B.v[1] = h2mul(LutR[(((cw >> 8) & 255u) << 5) | lb], s4[1]);
        B.v[2] = h2mul(LutR[(((cw >> 16) & 255u) << 5) | lb], s4[2]);
        B.v[3] = h2mul(LutR[((cw >> 24) << 5) | lb], s4[3]);
#pragma unroll
        for (int fm = 0; fm < 4; ++fm)
          acc[fm][j] = __builtin_amdgcn_mfma_f32_16x16x32_f16(a[fm].h, B.h, acc[fm][j], 0, 0, 0);
      }
    }
  };

  unsigned Xc[8], Yc[8];
  u32x4 Xs[2], Ys[2];

  stageA(0, 0);
  loadB(0, Xc, Xs);
  __syncthreads();  // LUT visible + chunk0 staged (vmcnt drained by barrier)

#pragma unroll 1
  for (int cc = 0; cc < 32; ++cc) {
    const int c0 = 2 * cc;
    stageA(c0 + 1, 1);                  // c0+1 <= 63 always
    loadB(c0 + 1, Yc, Ys);
    compute(0, Xc, Xs);
    __syncthreads();                    // buf0 consumed; buf1 staged
    if (cc < 31) {                      // chunk c0+2 exists only if cc<31
      stageA(c0 + 2, 0);
      loadB(c0 + 2, Xc, Xs);
    }
    compute(1, Yc, Ys);
    __syncthreads();                    // buf1 consumed; buf0 staged
  }

  // epilogue: C layout col=l15, row=kslice*4+r
#pragma unroll
  for (int j = 0; j < 4; ++j) {
    const int gc = n_tile + wnh * 64 + j * 16 + l15;
    const float bi = bias[gc];
#pragma unroll
    for (int fm = 0; fm < 4; ++fm) {
#pragma unroll
      for (int r = 0; r < 4; ++r) {
        const int gr = m_tile + wm2 * 64 + fm * 16 + kslice * 4 + r;
        out[(size_t)gr * N_DIM + gc] = acc[fm][j][r] + bi;
      }
    }
  }
}

// ---- fallback (round-1 kernel, proven 155us): used only if ws too small ----
#define FLDS 72
__global__ __launch_bounds__(256) void nf4_gemm_fused(
    const float* __restrict__ x, const int* __restrict__ packed,
    const float* __restrict__ scales, const float* __restrict__ bias,
    float* __restrict__ out) {
  __shared__ unsigned short AldsF[128 * FLDS];
  __shared__ unsigned short BldsF[128 * FLDS];
  __shared__ float2 Lut[256];
  const int t = threadIdx.x;
  const int bid = blockIdx.x;
  const int swz = (bid & 7) * 43 + (bid >> 3);
  const int m_tile = (swz / 86) * 128;
  const int n_tile = (swz % 86) * 128;
  Lut[t] = make_float2(NF4[(t >> 4) & 15], NF4[t & 15]);
  const int lane = t & 63;
  const int wid = t >> 6;
  const int wm = (wid >> 1) * 64;
  const int wn = (wid & 1) * 64;
  const int l15 = lane & 15;
  const int l4 = lane >> 4;
  f32x4 acc[4][4];
#pragma unroll
  for (int i = 0; i < 4; ++i)
#pragma unroll
    for (int j = 0; j < 4; ++j) acc[i][j] = (f32x4){0.f, 0.f, 0.f, 0.f};
  const int mlane = t & 15;
  const int n_sub = mlane * 8;
  const int k_sub = 4 * (((t >> 4) + mlane) & 15);
  const int c4 = t & 15;
  const int r0 = t >> 4;
  for (int k0 = 0; k0 < K_DIM; k0 += 64) {
    __syncthreads();
#pragma unroll
    for (int i = 0; i < 8; ++i) {
      const int row = r0 + 16 * i;
      f32x4 xv = *(const f32x4*)(x + (size_t)(m_tile + row) * K_DIM + k0 + c4 * 4);
      uint2 d;
      d.x = f2bf(xv[0]) | (f2bf(xv[1]) << 16);
      d.y = f2bf(xv[2]) | (f2bf(xv[3]) << 16);
      *(uint2*)(&AldsF[row * FLDS + c4 * 4]) = d;
    }
    {
      const int* pk = packed + (size_t)(k0 + k_sub) * PK_ROW + ((n_tile + n_sub) >> 1);
      i32x4 w[4];
      float s[4];
#pragma unroll
      for (int kk = 0; kk < 4; ++kk) {
        w[kk] = *(const i32x4*)(pk + (size_t)kk * PK_ROW);
        s[kk] = scales[(size_t)(k0 + k_sub + kk) * SC_ROW + ((n_tile + n_sub) >> 6)];
      }
      float v[4][8];
#pragma unroll
      for (int kk = 0; kk < 4; ++kk)
#pragma unroll
        for (int e = 0; e < 4; ++e) {
          const int b = w[kk][e] & 0xFF;
          const float2 p = Lut[b];
          v[kk][2 * e] = p.x * s[kk];
          v[kk][2 * e + 1] = p.y * s[kk];
        }
#pragma unroll
      for (int j = 0; j < 8; ++j) {
        uint2 d;
        d.x = f2bf(v[0][j]) | (f2bf(v[1][j]) << 16);
        d.y = f2bf(v[2][j]) | (f2bf(v[3][j]) << 16);
        *(uint2*)(&BldsF[(n_sub + j) * FLDS + k_sub]) = d;
      }
    }
    __syncthreads();
#pragma unroll
    for (int ks = 0; ks < 2; ++ks) {
      bf16x8 af[4], bfv[4];
#pragma unroll
      for (int fm = 0; fm < 4; ++fm)
        af[fm] = *(const bf16x8*)(&AldsF[(wm + fm * 16 + l15) * FLDS + ks * 32 + l4 * 8]);
#pragma unroll
      for (int fn = 0; fn < 4; ++fn)
        bfv[fn] = *(const bf16x8*)(&BldsF[(wn + fn * 16 + l15) * FLDS + ks * 32 + l4 * 8]);
#pragma unroll
      for (int fm = 0; fm < 4; ++fm)
#pragma unroll
        for (int fn = 0; fn < 4; ++fn)
          acc[fm][fn] = __builtin_amdgcn_mfma_f32_16x16x32_bf16(af[fm], bfv[fn], acc[fm][fn], 0, 0, 0);
    }
  }
#pragma unroll
  for (int fn = 0; fn < 4; ++fn) {
    const float bi = bias[n_tile + wn + fn * 16 + l15];
#pragma unroll
    for (int fm = 0; fm < 4; ++fm)
#pragma unroll
      for (int r = 0; r < 4; ++r) {
        const int gr = m_tile + wm + fm * 16 + l4 * 4 + r;
        out[(size_t)gr * N_DIM + n_tile + wn + fn * 16 + l15] = acc[fm][fn][r] + bi;
      }
  }
}

extern "C" void kernel_launch(void* const* d_in, const int* in_sizes, int n_in,
                              void* d_out, int out_size, void* d_ws, size_t ws_size,
                              hipStream_t stream) {
  const float* x = (const float*)d_in[0];
  const int* packed = (const int*)d_in[1];
  const float* scales = (const float*)d_in[2];
  const float* bias = (const float*)d_in[3];
  float* out = (float*)d_out;

  const size_t A_BYTES = (size_t)M_DIM * K_DIM * 2;            // 4,194,304
  const size_t C_BYTES = (size_t)688 * 512 * 16 * 4;           // 22,544,384
  const size_t S_BYTES = (size_t)SC_ROW * 2048 * 4;            // 1,409,024
  const size_t need = A_BYTES + C_BYTES + S_BYTES;

  if (ws_size >= need) {
    unsigned* wsa = (unsigned*)d_ws;
    unsigned* codes = (unsigned*)((char*)d_ws + A_BYTES);
    unsigned* scalesp = (unsigned*)((char*)d_ws + A_BYTES + C_BYTES);
    conv_a16<<<dim3(1024), dim3(256), 0, stream>>>(x, wsa);
    prep_codes<<<dim3(5504), dim3(256), 0, stream>>>(packed, codes);
    prep_scales<<<dim3(1376), dim3(256), 0, stream>>>(scales, scalesp);
    nf4_gemm16<<<dim3(344), dim3(256), 0, stream>>>(codes, scalesp, wsa, bias, out);
  } else {
    nf4_gemm_fused<<<dim3(344), dim3(256), 0, stream>>>(x, packed, scales, bias, out);
  }
}

// Round 9
// 102.168 us; speedup vs baseline: 1.2328x; 1.2328x over previous
//
#include <hip/hip_runtime.h>
#include <hip/hip_bf16.h>
#include <hip/hip_fp16.h>
#include <stdint.h>

#define K_DIM 4096
#define N_DIM 11008
#define M_DIM 512
#define PK_ROW 5504          // int32 code-words per k-row (one per n-pair)
#define SC_ROW 172           // scale blocks per k-row

typedef __attribute__((ext_vector_type(4))) float f32x4;
typedef __attribute__((ext_vector_type(4))) int i32x4;
typedef __attribute__((ext_vector_type(4))) unsigned int u32x4;
typedef __attribute__((ext_vector_type(8))) _Float16 half8;
typedef __attribute__((ext_vector_type(8))) short bf16x8;

__constant__ float NF4[16] = {
    -1.0f, -0.6961928009986877f, -0.5250730514526367f, -0.39491748809814453f,
    -0.28444138169288635f, -0.18477343022823334f, -0.09105003625154495f, 0.0f,
    0.07958029955625534f, 0.16093020141124725f, 0.24611230194568634f,
    0.33791524171829224f, 0.44070982933044434f, 0.5626170039176941f,
    0.7229568362236023f, 1.0f};

union H8 { u32x4 v; half8 h; };

__device__ __forceinline__ unsigned h2mul(unsigned a, unsigned b) {
  union { __half2 h; unsigned u; } x, y, r;
  x.u = a; y.u = b;
  r.h = x.h * y.h;           // v_pk_mul_f16
  return r.u;
}
__device__ __forceinline__ unsigned hpack(float a, float b) {
  union { __half2 h; unsigned u; } c;
  c.h = __floats2half2_rn(a, b);
  return c.u;
}
__device__ __forceinline__ unsigned f2bf(float v) {  // for fallback kernel
  union { __hip_bfloat16 h; unsigned short u; } cv;
  cv.h = __float2bfloat16(v);
  return (unsigned)cv.u;
}

// ---- pre-pass 1: x fp32 -> f16, MFMA-fragment-block layout ----
// unit (m16,k32) = 1KB; u32 idx = (m16*128+k32)*256 + lane*4
// lane l: A[m16*16+(l&15)][k32*32+(l>>4)*8 .. +8)
__global__ __launch_bounds__(256) void conv_a16(const float* __restrict__ x,
                                                unsigned* __restrict__ wsa) {
  const int wid = blockIdx.x * 4 + (threadIdx.x >> 6);
  const int lane = threadIdx.x & 63;
  const int m16 = wid >> 7, k32 = wid & 127;
  const int m = m16 * 16 + (lane & 15);
  const int k = k32 * 32 + (lane >> 4) * 8;
  const float* src = x + (size_t)m * K_DIM + k;
  f32x4 v0 = *(const f32x4*)src;
  f32x4 v1 = *(const f32x4*)(src + 4);
  u32x4 d;
  d[0] = hpack(v0[0], v0[1]);
  d[1] = hpack(v0[2], v0[3]);
  d[2] = hpack(v1[0], v1[1]);
  d[3] = hpack(v1[2], v1[3]);
  *(u32x4*)(wsa + (size_t)wid * 256 + lane * 4) = d;
}

// ---- pre-pass 2: transpose-compact codes ----
// out: uint8 byte (n, kp) = code(2kp,n)<<4 | code(2kp+1,n), stored as dwords:
//      dword D = ((n>>4)*512 + (kp>>2))*16 + (n&15)
__global__ __launch_bounds__(256) void prep_codes(const int* __restrict__ packed,
                                                  unsigned* __restrict__ codes) {
  const int b = blockIdx.x;
  const int kt = b & 63;   // k-tile of 64
  const int nt = b >> 6;   // n-tile of 128 (0..85)
  __shared__ unsigned char Sb[128 * 36];  // [n_local][kp_local], pad 36
  const int t = threadIdx.x;
  const int npl = t & 63;
  const int kq = t >> 6;
  const int np = nt * 64 + npl;
#pragma unroll
  for (int i = 0; i < 8; ++i) {
    const int kpl = kq + i * 4;               // 0..31
    const int k = kt * 64 + kpl * 2;
    const int w0 = packed[(size_t)k * PK_ROW + np];
    const int w1 = packed[(size_t)(k + 1) * PK_ROW + np];
    Sb[(npl * 2) * 36 + kpl] =
        (unsigned char)((((w0 >> 4) & 15) << 4) | ((w1 >> 4) & 15));  // even n
    Sb[(npl * 2 + 1) * 36 + kpl] =
        (unsigned char)(((w0 & 15) << 4) | (w1 & 15));                // odd n
  }
  __syncthreads();
#pragma unroll
  for (int i = 0; i < 4; ++i) {
    const int lin = t + 256 * i;              // 0..1023
    const int n16 = lin & 15;
    const int kp4l = (lin >> 4) & 7;
    const int nb16l = lin >> 7;               // 0..7
    const unsigned v = *(const unsigned*)(Sb + (nb16l * 16 + n16) * 36 + kp4l * 4);
    const size_t D = ((size_t)(nt * 8 + nb16l) * 512 + kt * 8 + kp4l) * 16 + n16;
    codes[D] = v;
  }
}

// ---- pre-pass 3: scales fp32 [k][nb] -> f16x2 pairs [nb][kp] ----
__global__ __launch_bounds__(256) void prep_scales(const float* __restrict__ scales,
                                                   unsigned* __restrict__ scalesp) {
  const int g = blockIdx.x * 256 + threadIdx.x;
  if (g >= SC_ROW * 2048) return;
  const int kp = g / SC_ROW;
  const int nb = g - kp * SC_ROW;
  const float s0 = scales[(size_t)(2 * kp) * SC_ROW + nb];
  const float s1 = scales[(size_t)(2 * kp + 1) * SC_ROW + nb];
  scalesp[(size_t)nb * 2048 + kp] = hpack(s0, s1);
}

// ---- main: barrier-free fused NF4 GEMM, f16 MFMA, K-split ----
// R9: wave 64m x 64n (acc 4x4), block 2x2 waves = 128x128. KS=2 splits K ->
// grid 688 -> 2752 waves (10.7/CU) — the occupancy K-split that R8 lacked
// (R8: 1376 waves, 168 CUs at 1 wave/SIMD serialized everything).
// A read VMEM-direct from fragment-layout ws (off the LDS pipe; 688MB,
// L1/L2-cached, XCD m-slice = 1MB L2-resident). LDS = replicated LUT only.
// No __syncthreads after init; 2-deep named prefetch.
template <int KS>
__global__ __launch_bounds__(256, 3) void nf4_gemm16(
    const unsigned* __restrict__ codes, const unsigned* __restrict__ scalesp,
    const unsigned* __restrict__ wsa, const float* __restrict__ bias,
    float* __restrict__ cout) {
  __shared__ unsigned LutR[256 * 32];  // 32-copy replicated LUT (0 conflicts)

  const int bid = blockIdx.x;
  const int x = bid & 7;
  const int local = bid >> 3;              // KS=2: 0..85, KS=1: 0..42
  const int kh = (KS == 2) ? (local & 1) : 0;
  const int q = (KS == 2) ? (local >> 1) : local;  // 0..42
  const int tile = x * 43 + q;             // 0..343; XCD x owns one m-slice
  const int m_tile = (tile / 86) * 128;
  const int n_tile = (tile % 86) * 128;

  const int t = threadIdx.x;
  {  // replicated LUT: dword idx = byte*32 + copy; lane uses copy=lane&31
    const int c = t & 31;
    const int b0 = t >> 5;
#pragma unroll
    for (int i = 0; i < 32; ++i) {
      const int b = b0 + 8 * i;
      LutR[b * 32 + c] = hpack(NF4[(b >> 4) & 15], NF4[b & 15]);
    }
  }
  __syncthreads();  // LUT visible; only barrier in the kernel

  const int lane = t & 63;
  const int wid = t >> 6;
  const int wm2 = wid >> 1;            // wave m-half (64 rows)
  const int wnh = wid & 1;             // wave n-half (64 cols)
  const int l15 = lane & 15;
  const int kslice = lane >> 4;
  const int lb = lane & 31;
  const int m16w = (m_tile >> 4) + wm2 * 4;
  const int nf0 = (n_tile >> 4) + wnh * 4;
  const int nb64 = (n_tile >> 6) + wnh;

  unsigned cb[4];
#pragma unroll
  for (int j = 0; j < 4; ++j) cb[j] = (unsigned)(nf0 + j) * 8192 + lane;
  const unsigned sb = (unsigned)nb64 * 2048 + kslice * 4;
  unsigned ab[4];
#pragma unroll
  for (int fm = 0; fm < 4; ++fm)
    ab[fm] = (unsigned)(m16w + fm) * 32768 + lane * 4;

  f32x4 acc[4][4];
#pragma unroll
  for (int i = 0; i < 4; ++i)
#pragma unroll
    for (int j = 0; j < 4; ++j) acc[i][j] = (f32x4){0.f, 0.f, 0.f, 0.f};

  const int NS = 128 / KS;             // 32k-steps per block
  const int s_base = kh * NS;

  auto LOAD = [&](int sl, unsigned* c, u32x4& sv, u32x4* A) {
    const unsigned s = (unsigned)(s_base + sl);
#pragma unroll
    for (int j = 0; j < 4; ++j) c[j] = codes[cb[j] + 64u * s];
    sv = *(const u32x4*)(scalesp + sb + 16u * s);
#pragma unroll
    for (int fm = 0; fm < 4; ++fm)
      A[fm] = *(const u32x4*)(wsa + ab[fm] + 256u * s);
  };
  auto STEP = [&](const unsigned* c, const u32x4& sv, const u32x4* A) {
    H8 a[4];
#pragma unroll
    for (int fm = 0; fm < 4; ++fm) a[fm].v = A[fm];
#pragma unroll
    for (int j = 0; j < 4; ++j) {
      const unsigned cw = c[j];
      H8 B;
      B.v[0] = h2mul(LutR[((cw & 255u) << 5) | lb], sv[0]);
      B.v[1] = h2mul(LutR[(((cw >> 8) & 255u) << 5) | lb], sv[1]);
      B.v[2] = h2mul(LutR[(((cw >> 16) & 255u) << 5) | lb], sv[2]);
      B.v[3] = h2mul(LutR[((cw >> 24) << 5) | lb], sv[3]);
#pragma unroll
      for (int fm = 0; fm < 4; ++fm)
        acc[fm][j] = __builtin_amdgcn_mfma_f32_16x16x32_f16(a[fm].h, B.h, acc[fm][j], 0, 0, 0);
    }
  };

  unsigned Xc[4], Yc[4];
  u32x4 Xs, Ys;
  u32x4 XA[4], YA[4];
  LOAD(0, Xc, Xs, XA);
#pragma unroll 1
  for (int s = 0; s < NS; s += 2) {
    LOAD(s + 1, Yc, Ys, YA);           // s+1 <= NS-1 always
    STEP(Xc, Xs, XA);
    if (s + 2 < NS) LOAD(s + 2, Xc, Xs, XA);
    STEP(Yc, Ys, YA);
  }

  // epilogue: C layout col=l15, row=kslice*4+r
  float* dst = cout + (KS == 2 ? (size_t)kh * ((size_t)M_DIM * N_DIM) : 0);
#pragma unroll
  for (int j = 0; j < 4; ++j) {
    const int gc = n_tile + wnh * 64 + j * 16 + l15;
    const float bi = (KS == 1) ? bias[gc] : 0.f;
#pragma unroll
    for (int fm = 0; fm < 4; ++fm) {
#pragma unroll
      for (int r = 0; r < 4; ++r) {
        const int gr = m_tile + wm2 * 64 + fm * 16 + kslice * 4 + r;
        dst[(size_t)gr * N_DIM + gc] = acc[fm][j][r] + bi;
      }
    }
  }
}

// ---- reduce: out = c0 + c1 + bias ----
__global__ __launch_bounds__(256) void reduce_bias(
    const float* __restrict__ c0, const float* __restrict__ c1,
    const float* __restrict__ bias, float* __restrict__ out) {
  const int tot4 = (M_DIM * N_DIM) / 4;  // 1,409,024 float4
  const int stride = gridDim.x * 256;
  for (int i = blockIdx.x * 256 + threadIdx.x; i < tot4; i += stride) {
    const int e0 = i * 4;
    const int col = e0 % N_DIM;          // N_DIM % 4 == 0 -> 16B aligned
    f32x4 a = *(const f32x4*)(c0 + e0);
    f32x4 b = *(const f32x4*)(c1 + e0);
    f32x4 bi = *(const f32x4*)(bias + col);
    *(f32x4*)(out + e0) = a + b + bi;
  }
}

// ---- fallback (round-1 kernel, proven 155us): used only if ws tiny ----
#define FLDS 72
__global__ __launch_bounds__(256) void nf4_gemm_fused(
    const float* __restrict__ x, const int* __restrict__ packed,
    const float* __restrict__ scales, const float* __restrict__ bias,
    float* __restrict__ out) {
  __shared__ unsigned short AldsF[128 * FLDS];
  __shared__ unsigned short BldsF[128 * FLDS];
  __shared__ float2 Lut[256];
  const int t = threadIdx.x;
  const int bid = blockIdx.x;
  const int swz = (bid & 7) * 43 + (bid >> 3);
  const int m_tile = (swz / 86) * 128;
  const int n_tile = (swz % 86) * 128;
  Lut[t] = make_float2(NF4[(t >> 4) & 15], NF4[t & 15]);
  const int lane = t & 63;
  const int wid = t >> 6;
  const int wm = (wid >> 1) * 64;
  const int wn = (wid & 1) * 64;
  const int l15 = lane & 15;
  const int l4 = lane >> 4;
  f32x4 acc[4][4];
#pragma unroll
  for (int i = 0; i < 4; ++i)
#pragma unroll
    for (int j = 0; j < 4; ++j) acc[i][j] = (f32x4){0.f, 0.f, 0.f, 0.f};
  const int mlane = t & 15;
  const int n_sub = mlane * 8;
  const int k_sub = 4 * (((t >> 4) + mlane) & 15);
  const int c4 = t & 15;
  const int r0 = t >> 4;
  for (int k0 = 0; k0 < K_DIM; k0 += 64) {
    __syncthreads();
#pragma unroll
    for (int i = 0; i < 8; ++i) {
      const int row = r0 + 16 * i;
      f32x4 xv = *(const f32x4*)(x + (size_t)(m_tile + row) * K_DIM + k0 + c4 * 4);
      uint2 d;
      d.x = f2bf(xv[0]) | (f2bf(xv[1]) << 16);
      d.y = f2bf(xv[2]) | (f2bf(xv[3]) << 16);
      *(uint2*)(&AldsF[row * FLDS + c4 * 4]) = d;
    }
    {
      const int* pk = packed + (size_t)(k0 + k_sub) * PK_ROW + ((n_tile + n_sub) >> 1);
      i32x4 w[4];
      float s[4];
#pragma unroll
      for (int kk = 0; kk < 4; ++kk) {
        w[kk] = *(const i32x4*)(pk + (size_t)kk * PK_ROW);
        s[kk] = scales[(size_t)(k0 + k_sub + kk) * SC_ROW + ((n_tile + n_sub) >> 6)];
      }
      float v[4][8];
#pragma unroll
      for (int kk = 0; kk < 4; ++kk)
#pragma unroll
        for (int e = 0; e < 4; ++e) {
          const int b = w[kk][e] & 0xFF;
          const float2 p = Lut[b];
          v[kk][2 * e] = p.x * s[kk];
          v[kk][2 * e + 1] = p.y * s[kk];
        }
#pragma unroll
      for (int j = 0; j < 8; ++j) {
        uint2 d;
        d.x = f2bf(v[0][j]) | (f2bf(v[1][j]) << 16);
        d.y = f2bf(v[2][j]) | (f2bf(v[3][j]) << 16);
        *(uint2*)(&BldsF[(n_sub + j) * FLDS + k_sub]) = d;
      }
    }
    __syncthreads();
#pragma unroll
    for (int ks = 0; ks < 2; ++ks) {
      bf16x8 af[4], bfv[4];
#pragma unroll
      for (int fm = 0; fm < 4; ++fm)
        af[fm] = *(const bf16x8*)(&AldsF[(wm + fm * 16 + l15) * FLDS + ks * 32 + l4 * 8]);
#pragma unroll
      for (int fn = 0; fn < 4; ++fn)
        bfv[fn] = *(const bf16x8*)(&BldsF[(wn + fn * 16 + l15) * FLDS + ks * 32 + l4 * 8]);
#pragma unroll
      for (int fm = 0; fm < 4; ++fm)
#pragma unroll
        for (int fn = 0; fn < 4; ++fn)
          acc[fm][fn] = __builtin_amdgcn_mfma_f32_16x16x32_bf16(af[fm], bfv[fn], acc[fm][fn], 0, 0, 0);
    }
  }
#pragma unroll
  for (int fn = 0; fn < 4; ++fn) {
    const float bi = bias[n_tile + wn + fn * 16 + l15];
#pragma unroll
    for (int fm = 0; fm < 4; ++fm)
#pragma unroll
      for (int r = 0; r < 4; ++r) {
        const int gr = m_tile + wm + fm * 16 + l4 * 4 + r;
        out[(size_t)gr * N_DIM + n_tile + wn + fn * 16 + l15] = acc[fm][fn][r] + bi;
      }
  }
}

extern "C" void kernel_launch(void* const* d_in, const int* in_sizes, int n_in,
                              void* d_out, int out_size, void* d_ws, size_t ws_size,
                              hipStream_t stream) {
  const float* x = (const float*)d_in[0];
  const int* packed = (const int*)d_in[1];
  const float* scales = (const float*)d_in[2];
  const float* bias = (const float*)d_in[3];
  float* out = (float*)d_out;

  const size_t A_BYTES = (size_t)M_DIM * K_DIM * 2;            // 4,194,304
  const size_t C_BYTES = (size_t)688 * 512 * 16 * 4;           // 22,544,384
  const size_t S_BYTES = (size_t)SC_ROW * 2048 * 4;            // 1,409,024
  const size_t P_BYTES = (size_t)2 * M_DIM * N_DIM * 4;        // 45,088,768
  const size_t need1 = A_BYTES + C_BYTES + S_BYTES;            // 28.1 MB
  const size_t need2 = need1 + P_BYTES;                        // 73.2 MB

  if (ws_size >= need1) {
    unsigned* wsa = (unsigned*)d_ws;
    unsigned* codes = (unsigned*)((char*)d_ws + A_BYTES);
    unsigned* scalesp = (unsigned*)((char*)d_ws + A_BYTES + C_BYTES);
    conv_a16<<<dim3(1024), dim3(256), 0, stream>>>(x, wsa);
    prep_codes<<<dim3(5504), dim3(256), 0, stream>>>(packed, codes);
    prep_scales<<<dim3(1376), dim3(256), 0, stream>>>(scales, scalesp);
    if (ws_size >= need2) {
      float* cpart = (float*)((char*)d_ws + need1);
      nf4_gemm16<2><<<dim3(688), dim3(256), 0, stream>>>(codes, scalesp, wsa, bias, cpart);
      reduce_bias<<<dim3(2048), dim3(256), 0, stream>>>(
          cpart, cpart + (size_t)M_DIM * N_DIM, bias, out);
    } else {
      nf4_gemm16<1><<<dim3(344), dim3(256), 0, stream>>>(codes, scalesp, wsa, bias, out);
    }
  } else {
    nf4_gemm_fused<<<dim3(344), dim3(256), 0, stream>>>(x, packed, scales, bias, out);
  }
}